// Round 11
// baseline (252.207 us; speedup 1.0000x reference)
//
#include <hip/hip_runtime.h>
#include <hip/hip_fp8.h>
#include <math.h>

#define NN 100000
#define NE 1600000
#define SBN 512                      // nodes per super-bucket
#define NSB ((NN + SBN - 1) / SBN)   // 196 super-buckets
#define SBCAP 10240                  // per-super-bucket edge capacity (mean 8192)
#define EPB 8192                     // edges per binA block
#define NBA ((NE + EPB - 1) / EPB)   // 196 binA blocks

typedef __attribute__((ext_vector_type(8))) short bf16x8;   // 8 bf16 = 4 VGPR (MFMA A/B frag)
typedef __attribute__((ext_vector_type(8))) unsigned short ush8;
typedef __attribute__((ext_vector_type(4))) float f32x4;    // MFMA C/D frag

static __device__ __forceinline__ float b2f(unsigned short u) {
    return __uint_as_float(((unsigned int)u) << 16);
}
static __device__ __forceinline__ unsigned short f2bf(float f) {
    unsigned int u = __float_as_uint(f);
    u += 0x7fffu + ((u >> 16) & 1u);   // RNE
    return (unsigned short)(u >> 16);
}
static __device__ __forceinline__ unsigned char f2fp8(float f) {
    __hip_fp8_e4m3 q(f);
    return (unsigned char)q.__x;
}
// accumulate 4 fp8 (one u32) into acc[0..3]
static __device__ __forceinline__ void fp8x4_acc(unsigned int w, float* acc) {
#if __has_builtin(__builtin_amdgcn_cvt_pk_f32_fp8)
    auto lo = __builtin_amdgcn_cvt_pk_f32_fp8(w, false);
    auto hi = __builtin_amdgcn_cvt_pk_f32_fp8(w, true);
    acc[0] += lo[0]; acc[1] += lo[1]; acc[2] += hi[0]; acc[3] += hi[1];
#else
    #pragma unroll
    for (int k = 0; k < 4; ++k) {
        __hip_fp8_e4m3 q; q.__x = (__hip_fp8_storage_t)((w >> (8 * k)) & 0xffu);
        acc[k] += (float)q;
    }
#endif
}

// ---------------- conversions ----------------
// x f32 -> xb bf16 AND xq fp8 in one pass
__global__ __launch_bounds__(256)
void k_cvt_x(const float* __restrict__ in, unsigned short* __restrict__ outb,
             unsigned char* __restrict__ outq, long total8) {
    long i = (long)blockIdx.x * 256 + threadIdx.x;
    long stride = (long)gridDim.x * 256;
    for (; i < total8; i += stride) {
        const float4* p = (const float4*)(in + i * 8);
        float4 a = p[0], b = p[1];
        ush8 r;
        r[0] = f2bf(a.x); r[1] = f2bf(a.y); r[2] = f2bf(a.z); r[3] = f2bf(a.w);
        r[4] = f2bf(b.x); r[5] = f2bf(b.y); r[6] = f2bf(b.z); r[7] = f2bf(b.w);
        *(ush8*)(outb + i * 8) = r;
        unsigned int q0 = (unsigned int)f2fp8(a.x) | ((unsigned int)f2fp8(a.y) << 8) |
                          ((unsigned int)f2fp8(a.z) << 16) | ((unsigned int)f2fp8(a.w) << 24);
        unsigned int q1 = (unsigned int)f2fp8(b.x) | ((unsigned int)f2fp8(b.y) << 8) |
                          ((unsigned int)f2fp8(b.z) << 16) | ((unsigned int)f2fp8(b.w) << 24);
        uint2 q = make_uint2(q0, q1);
        *(uint2*)(outq + i * 8) = q;
    }
}

// W [128, N] f32 -> Wt [N, 128] bf16 (row-major over n)
__global__ __launch_bounds__(256)
void k_cvt_w(const float* __restrict__ W, unsigned short* __restrict__ Wt, int N) {
    int id = blockIdx.x * 256 + threadIdx.x;
    if (id < N * 128) {
        int n = id >> 7, k = id & 127;
        Wt[id] = f2bf(W[k * N + n]);
    }
}

// Wtcat[n][k]: n<64 -> W2l[k][n], else W2r[k][n-64]   (both [128,64] f32)
__global__ __launch_bounds__(256)
void k_cvt_wcat(const float* __restrict__ W2l, const float* __restrict__ W2r,
                unsigned short* __restrict__ Wt) {
    int id = blockIdx.x * 256 + threadIdx.x;
    if (id < 128 * 128) {
        int n = id >> 7, k = id & 127;
        float v = (n < 64) ? W2l[k * 64 + n] : W2r[k * 64 + (n - 64)];
        Wt[id] = f2bf(v);
    }
}

// ---------------- pass A: LDS-binned counting sort into 196 super-buckets ----------------
__global__ __launch_bounds__(1024)
void k_binA(const int* __restrict__ src, const int* __restrict__ dst,
            int* __restrict__ gcnt, int* __restrict__ pairs) {
    __shared__ int lsort[EPB];        // 32 KB
    __shared__ int lhist[256];
    __shared__ int lofs[256];         // exclusive offsets (immutable copy)
    __shared__ int lpos[NSB];
    __shared__ int gbase[NSB];
    const int tid = threadIdx.x;
    const int base = blockIdx.x * EPB;
    const int cnt = min(EPB, NE - base);

    int v[8], bn[8];
    #pragma unroll
    for (int k = 0; k < 8; ++k) {
        int i = k * 1024 + tid;
        if (i < cnt) {
            int d = dst[base + i], s = src[base + i];
            v[k] = (s << 9) | (d & 511);
            bn[k] = d >> 9;
        } else bn[k] = -1;
    }
    if (tid < 256) lhist[tid] = 0;
    __syncthreads();
    #pragma unroll
    for (int k = 0; k < 8; ++k) if (bn[k] >= 0) atomicAdd(&lhist[bn[k]], 1);
    __syncthreads();
    if (tid < 256) lofs[tid] = lhist[tid];
    __syncthreads();
    for (int d = 1; d < 256; d <<= 1) {
        int u = (tid < 256 && tid >= d) ? lofs[tid - d] : 0;
        __syncthreads();
        if (tid < 256) lofs[tid] += u;
        __syncthreads();
    }
    if (tid < 256) lofs[tid] -= lhist[tid];   // inclusive -> exclusive
    __syncthreads();
    if (tid < NSB) {
        lpos[tid] = lofs[tid];
        gbase[tid] = atomicAdd(&gcnt[tid], lhist[tid]);
    }
    __syncthreads();
    #pragma unroll
    for (int k = 0; k < 8; ++k) if (bn[k] >= 0) {
        int slot = atomicAdd(&lpos[bn[k]], 1);
        lsort[slot] = v[k];
    }
    __syncthreads();
    for (int i = tid; i < cnt; i += 1024) {
        int lo = 0, hi = NSB - 1;
        while (lo < hi) { int mid = (lo + hi + 1) >> 1; if (lofs[mid] <= i) lo = mid; else hi = mid - 1; }
        int off = gbase[lo] + (i - lofs[lo]);
        if (off < SBCAP)
            __builtin_nontemporal_store(lsort[i], &pairs[(size_t)lo * SBCAP + off]);
    }
}

// ---------------- pass B: per-super-bucket sort -> CSR (in place), deg/offs ----------------
__global__ __launch_bounds__(1024)
void k_sortB(const int* __restrict__ gcnt, int* __restrict__ pairs,
             int* __restrict__ offs, int* __restrict__ deg) {
    __shared__ int lstage[SBCAP];     // 40 KB
    __shared__ int lhist[SBN], lscan[SBN], lpos[SBN];
    const int sb = blockIdx.x, tid = threadIdx.x;
    const int cnt = min(gcnt[sb], SBCAP);
    int* __restrict__ region = pairs + (size_t)sb * SBCAP;

    for (int i = tid; i < cnt; i += 1024) lstage[i] = region[i];
    if (tid < SBN) lhist[tid] = 0;
    __syncthreads();
    for (int i = tid; i < cnt; i += 1024) atomicAdd(&lhist[lstage[i] & 511], 1);
    __syncthreads();
    if (tid < SBN) lscan[tid] = lhist[tid];
    __syncthreads();
    for (int d = 1; d < SBN; d <<= 1) {
        int u = (tid < SBN && tid >= d) ? lscan[tid - d] : 0;
        __syncthreads();
        if (tid < SBN) lscan[tid] += u;
        __syncthreads();
    }
    if (tid < SBN) {
        int ex = lscan[tid] - lhist[tid];
        lpos[tid] = ex;
        int node = sb * SBN + tid;
        if (node < NN) { offs[node] = sb * SBCAP + ex; deg[node] = lhist[tid]; }
    }
    __syncthreads();
    for (int i = tid; i < cnt; i += 1024) {
        int val = lstage[i];
        int slot = atomicAdd(&lpos[val & 511], 1);
        region[slot] = val >> 9;
    }
}

// ---------------- fp8 mean aggregation (layer 1): 8-lane groups, 8 edges/instr ----------------
// Row = 128 fp8 = 128B = 8 lanes x 16B. Output meanb bf16 (feeds MFMA GEMM).
__global__ __launch_bounds__(256)
void k_aggregate_f8(const unsigned char* __restrict__ featq, const int* __restrict__ csr,
                    const int* __restrict__ offs, const int* __restrict__ deg,
                    unsigned short* __restrict__ outmean) {
    const int wid = threadIdx.x >> 6, lane = threadIdx.x & 63;
    const int g8 = lane >> 3, l8 = lane & 7;
    const int node = blockIdx.x * 4 + wid;
    if (node >= NN) return;
    int off = __builtin_amdgcn_readfirstlane(offs[node]);
    int dg  = __builtin_amdgcn_readfirstlane(deg[node]);
    const uint4* __restrict__ f16b = (const uint4*)featq;   // 16 fp8 per uint4
    float acc[16];
    #pragma unroll
    for (int i = 0; i < 16; ++i) acc[i] = 0.f;
    int j = 0;
    for (; j + 16 <= dg; j += 16) {
        int e0 = csr[off + j + g8];
        int e1 = csr[off + j + 8 + g8];
        uint4 v0 = f16b[(size_t)e0 * 8 + l8];
        uint4 v1 = f16b[(size_t)e1 * 8 + l8];
        fp8x4_acc(v0.x, acc); fp8x4_acc(v0.y, acc + 4);
        fp8x4_acc(v0.z, acc + 8); fp8x4_acc(v0.w, acc + 12);
        fp8x4_acc(v1.x, acc); fp8x4_acc(v1.y, acc + 4);
        fp8x4_acc(v1.z, acc + 8); fp8x4_acc(v1.w, acc + 12);
    }
    for (; j + 8 <= dg; j += 8) {
        int e0 = csr[off + j + g8];
        uint4 v0 = f16b[(size_t)e0 * 8 + l8];
        fp8x4_acc(v0.x, acc); fp8x4_acc(v0.y, acc + 4);
        fp8x4_acc(v0.z, acc + 8); fp8x4_acc(v0.w, acc + 12);
    }
    int rem = dg - j;
    if (g8 < rem) {
        int e0 = csr[off + j + g8];
        uint4 v0 = f16b[(size_t)e0 * 8 + l8];
        fp8x4_acc(v0.x, acc); fp8x4_acc(v0.y, acc + 4);
        fp8x4_acc(v0.z, acc + 8); fp8x4_acc(v0.w, acc + 12);
    }
    #pragma unroll
    for (int i = 0; i < 16; ++i) {
        acc[i] += __shfl_xor(acc[i], 8);
        acc[i] += __shfl_xor(acc[i], 16);
        acc[i] += __shfl_xor(acc[i], 32);
    }
    if (g8 == 0) {
        float inv = 1.0f / (float)(dg > 0 ? dg : 1);
        ush8 r0, r1;
        #pragma unroll
        for (int i = 0; i < 8; ++i) { r0[i] = f2bf(acc[i] * inv); r1[i] = f2bf(acc[i + 8] * inv); }
        ((ush8*)outmean)[(size_t)node * 16 + l8 * 2]     = r0;
        ((ush8*)outmean)[(size_t)node * 16 + l8 * 2 + 1] = r1;
    }
}

// ---------------- MFMA dual GEMM (layer 1): hb = relu(Am@Wl + Ax@Wr + b1) ----------------
template <int BN, bool RELU, bool OUTBF>
__global__ __launch_bounds__(256)
void k_gemm_mfma(const unsigned short* __restrict__ Am, const unsigned short* __restrict__ Ax,
                 const unsigned short* __restrict__ Wtl, const unsigned short* __restrict__ Wtr,
                 const float* __restrict__ bias, void* __restrict__ outp) {
    constexpr int BM = 128;
    constexpr int WAVES_N = BN / 64;
    constexpr int WAVES_M = 4 / WAVES_N;
    constexpr int MR = BM / (WAVES_M * 16);
    constexpr int NR = 4;
    __shared__ __align__(16) short As[BM * 40];
    __shared__ __align__(16) short Ws[BN * 40];

    const int tid = threadIdx.x;
    const int wave = tid >> 6, lane = tid & 63;
    const int l15 = lane & 15, kg = lane >> 4;
    const int wc = wave % WAVES_N, wr = wave / WAVES_N;
    const int rowbase = wr * MR * 16;
    const int colbase = wc * 64;
    const int row0 = blockIdx.x * BM;

    f32x4 acc[MR][NR];
    #pragma unroll
    for (int mr = 0; mr < MR; ++mr)
        #pragma unroll
        for (int nr = 0; nr < NR; ++nr) acc[mr][nr] = (f32x4){0.f, 0.f, 0.f, 0.f};

    for (int s = 0; s < 2; ++s) {
        const unsigned short* __restrict__ A  = s ? Ax : Am;
        const unsigned short* __restrict__ Wt = s ? Wtr : Wtl;
        for (int kc = 0; kc < 128; kc += 32) {
            __syncthreads();
            #pragma unroll
            for (int i = 0; i < (BM * 4) / 256; ++i) {
                int c = tid + 256 * i; int r = c >> 2, g = c & 3;
                ush8 v = {0, 0, 0, 0, 0, 0, 0, 0};
                int grow = row0 + r;
                if (grow < NN) v = *(const ush8*)&A[(size_t)grow * 128 + kc + g * 8];
                *(ush8*)&As[r * 40 + g * 8] = v;
            }
            #pragma unroll
            for (int i = 0; i < (BN * 4) / 256; ++i) {
                int c = tid + 256 * i; int n = c >> 2, g = c & 3;
                *(ush8*)&Ws[n * 40 + g * 8] = *(const ush8*)&Wt[n * 128 + kc + g * 8];
            }
            __syncthreads();
            bf16x8 af[MR], bfr[NR];
            #pragma unroll
            for (int mr = 0; mr < MR; ++mr)
                af[mr] = *(const bf16x8*)&As[(rowbase + mr * 16 + l15) * 40 + kg * 8];
            #pragma unroll
            for (int nr = 0; nr < NR; ++nr)
                bfr[nr] = *(const bf16x8*)&Ws[(colbase + nr * 16 + l15) * 40 + kg * 8];
            #pragma unroll
            for (int mr = 0; mr < MR; ++mr)
                #pragma unroll
                for (int nr = 0; nr < NR; ++nr)
                    acc[mr][nr] = __builtin_amdgcn_mfma_f32_16x16x32_bf16(
                        af[mr], bfr[nr], acc[mr][nr], 0, 0, 0);
        }
    }
    const int r4 = kg * 4;
    #pragma unroll
    for (int mr = 0; mr < MR; ++mr) {
        #pragma unroll
        for (int nr = 0; nr < NR; ++nr) {
            int col = colbase + nr * 16 + l15;
            float bv = bias[col];
            #pragma unroll
            for (int j = 0; j < 4; ++j) {
                int row = row0 + rowbase + mr * 16 + r4 + j;
                if (row < NN) {
                    float v = acc[mr][nr][j] + bv;
                    if (RELU) v = fmaxf(v, 0.f);
                    if (OUTBF) ((unsigned short*)outp)[(size_t)row * BN + col] = f2bf(v);
                    else       ((float*)outp)[(size_t)row * BN + col] = v;
                }
            }
        }
    }
}

// ---------------- cat GEMM (layer 2): g = hb@W2l (fp8), z = hb@W2r + b2 (bf16) ----------------
__global__ __launch_bounds__(256)
void k_gemm_cat(const unsigned short* __restrict__ A, const unsigned short* __restrict__ Wt,
                const float* __restrict__ b2,
                unsigned char* __restrict__ g, unsigned short* __restrict__ z) {
    constexpr int BM = 128, BN = 128, MR = 4, NR = 4;
    __shared__ __align__(16) short As[BM * 40];
    __shared__ __align__(16) short Ws[BN * 40];

    const int tid = threadIdx.x;
    const int wave = tid >> 6, lane = tid & 63;
    const int l15 = lane & 15, kg = lane >> 4;
    const int wc = wave % 2, wr = wave / 2;
    const int rowbase = wr * MR * 16;
    const int colbase = wc * 64;
    const int row0 = blockIdx.x * BM;

    f32x4 acc[MR][NR];
    #pragma unroll
    for (int mr = 0; mr < MR; ++mr)
        #pragma unroll
        for (int nr = 0; nr < NR; ++nr) acc[mr][nr] = (f32x4){0.f, 0.f, 0.f, 0.f};

    for (int kc = 0; kc < 128; kc += 32) {
        __syncthreads();
        #pragma unroll
        for (int i = 0; i < 2; ++i) {
            int c = tid + 256 * i; int r = c >> 2, gg = c & 3;
            ush8 v = {0, 0, 0, 0, 0, 0, 0, 0};
            int grow = row0 + r;
            if (grow < NN) v = *(const ush8*)&A[(size_t)grow * 128 + kc + gg * 8];
            *(ush8*)&As[r * 40 + gg * 8] = v;
        }
        #pragma unroll
        for (int i = 0; i < 2; ++i) {
            int c = tid + 256 * i; int n = c >> 2, gg = c & 3;
            *(ush8*)&Ws[n * 40 + gg * 8] = *(const ush8*)&Wt[n * 128 + kc + gg * 8];
        }
        __syncthreads();
        bf16x8 af[MR], bfr[NR];
        #pragma unroll
        for (int mr = 0; mr < MR; ++mr)
            af[mr] = *(const bf16x8*)&As[(rowbase + mr * 16 + l15) * 40 + kg * 8];
        #pragma unroll
        for (int nr = 0; nr < NR; ++nr)
            bfr[nr] = *(const bf16x8*)&Ws[(colbase + nr * 16 + l15) * 40 + kg * 8];
        #pragma unroll
        for (int mr = 0; mr < MR; ++mr)
            #pragma unroll
            for (int nr = 0; nr < NR; ++nr)
                acc[mr][nr] = __builtin_amdgcn_mfma_f32_16x16x32_bf16(
                    af[mr], bfr[nr], acc[mr][nr], 0, 0, 0);
    }
    const int r4 = kg * 4;
    #pragma unroll
    for (int mr = 0; mr < MR; ++mr) {
        #pragma unroll
        for (int nr = 0; nr < NR; ++nr) {
            int col = colbase + nr * 16 + l15;
            float bv = (col >= 64) ? b2[col - 64] : 0.f;
            #pragma unroll
            for (int j = 0; j < 4; ++j) {
                int row = row0 + rowbase + mr * 16 + r4 + j;
                if (row < NN) {
                    float v = acc[mr][nr][j] + bv;
                    if (col < 64) g[(size_t)row * 64 + col] = f2fp8(v);
                    else          z[(size_t)row * 64 + (col - 64)] = f2bf(v);
                }
            }
        }
    }
}

// ---------------- fused layer-2 tail: out = log_softmax(mean(g) + z) ----------------
// g rows = 64 fp8 = 64B = 4 lanes x 16B -> 16 edges/instr, unroll 2.
__global__ __launch_bounds__(256)
void k_agg_lsm(const unsigned char* __restrict__ gbuf, const unsigned short* __restrict__ zbuf,
               const int* __restrict__ csr, const int* __restrict__ offs,
               const int* __restrict__ deg, float* __restrict__ out) {
    const int wid = threadIdx.x >> 6, lane = threadIdx.x & 63;
    const int g16 = lane >> 2, l4 = lane & 3;
    const int node = blockIdx.x * 4 + wid;
    if (node >= NN) return;
    int off = __builtin_amdgcn_readfirstlane(offs[node]);
    int dg  = __builtin_amdgcn_readfirstlane(deg[node]);
    const uint4* __restrict__ f16b = (const uint4*)gbuf;   // 16 fp8 per uint4
    float acc[16];
    #pragma unroll
    for (int i = 0; i < 16; ++i) acc[i] = 0.f;
    int j = 0;
    for (; j + 32 <= dg; j += 32) {
        int e0 = csr[off + j + g16];
        int e1 = csr[off + j + 16 + g16];
        uint4 v0 = f16b[(size_t)e0 * 4 + l4];
        uint4 v1 = f16b[(size_t)e1 * 4 + l4];
        fp8x4_acc(v0.x, acc); fp8x4_acc(v0.y, acc + 4);
        fp8x4_acc(v0.z, acc + 8); fp8x4_acc(v0.w, acc + 12);
        fp8x4_acc(v1.x, acc); fp8x4_acc(v1.y, acc + 4);
        fp8x4_acc(v1.z, acc + 8); fp8x4_acc(v1.w, acc + 12);
    }
    for (; j + 16 <= dg; j += 16) {
        int e0 = csr[off + j + g16];
        uint4 v0 = f16b[(size_t)e0 * 4 + l4];
        fp8x4_acc(v0.x, acc); fp8x4_acc(v0.y, acc + 4);
        fp8x4_acc(v0.z, acc + 8); fp8x4_acc(v0.w, acc + 12);
    }
    int rem = dg - j;
    if (g16 < rem) {
        int e0 = csr[off + j + g16];
        uint4 v0 = f16b[(size_t)e0 * 4 + l4];
        fp8x4_acc(v0.x, acc); fp8x4_acc(v0.y, acc + 4);
        fp8x4_acc(v0.z, acc + 8); fp8x4_acc(v0.w, acc + 12);
    }
    #pragma unroll
    for (int i = 0; i < 16; ++i) {
        acc[i] += __shfl_xor(acc[i], 4);
        acc[i] += __shfl_xor(acc[i], 8);
        acc[i] += __shfl_xor(acc[i], 16);
        acc[i] += __shfl_xor(acc[i], 32);
    }
    float inv = 1.0f / (float)(dg > 0 ? dg : 1);
    ush8 z0 = ((const ush8*)zbuf)[(size_t)node * 8 + l4 * 2];
    ush8 z1 = ((const ush8*)zbuf)[(size_t)node * 8 + l4 * 2 + 1];
    float v[16];
    float m = -1e30f;
    #pragma unroll
    for (int i = 0; i < 8; ++i) {
        v[i]     = acc[i] * inv + b2f(z0[i]);
        v[i + 8] = acc[i + 8] * inv + b2f(z1[i]);
    }
    #pragma unroll
    for (int i = 0; i < 16; ++i) m = fmaxf(m, v[i]);
    #pragma unroll
    for (int d = 2; d >= 1; d >>= 1) m = fmaxf(m, __shfl_xor(m, d));
    float ss = 0.f;
    #pragma unroll
    for (int i = 0; i < 16; ++i) ss += __expf(v[i] - m);
    #pragma unroll
    for (int d = 2; d >= 1; d >>= 1) ss += __shfl_xor(ss, d);
    float lse = m + logf(ss);
    if (g16 == 0) {
        #pragma unroll
        for (int c = 0; c < 4; ++c) {
            float4 o = make_float4(v[c*4] - lse, v[c*4+1] - lse, v[c*4+2] - lse, v[c*4+3] - lse);
            *(float4*)&out[(size_t)node * 64 + l4 * 16 + c * 4] = o;
        }
    }
}

// ---------------- launch ----------------
extern "C" void kernel_launch(void* const* d_in, const int* in_sizes, int n_in,
                              void* d_out, int out_size, void* d_ws, size_t ws_size,
                              hipStream_t stream) {
    const float* x   = (const float*)d_in[0];
    const int* edges = (const int*)d_in[1];
    const float* W1l = (const float*)d_in[2];
    const float* b1  = (const float*)d_in[3];
    const float* W1r = (const float*)d_in[4];
    const float* W2l = (const float*)d_in[5];
    const float* b2  = (const float*)d_in[6];
    const float* W2r = (const float*)d_in[7];
    float* out = (float*)d_out;

    const int* src = edges;            // edge_index[0]
    const int* dst = edges + NE;       // edge_index[1]

    char* ws = (char*)d_ws;
    size_t o = 0;
    auto alloc = [&](size_t bytes) -> void* {
        void* p = ws + o;
        o = (o + bytes + 255) & ~(size_t)255;
        return p;
    };
    int* gcnt  = (int*)alloc((size_t)NSB * 4);
    int* pairs = (int*)alloc((size_t)NSB * SBCAP * 4);   // becomes CSR after sortB
    int* offs  = (int*)alloc((size_t)NN * 4);
    int* deg   = (int*)alloc((size_t)NN * 4);
    unsigned short* xb    = (unsigned short*)alloc((size_t)NN * 128 * 2);
    unsigned char*  xq    = (unsigned char*)alloc((size_t)NN * 128);
    unsigned short* meanb = (unsigned short*)alloc((size_t)NN * 128 * 2);
    unsigned short* hb    = (unsigned short*)alloc((size_t)NN * 128 * 2);
    unsigned char*  gbuf  = (unsigned char*)alloc((size_t)NN * 64);
    unsigned short* zbuf  = (unsigned short*)alloc((size_t)NN * 64 * 2);
    unsigned short* Wt1l  = (unsigned short*)alloc(128 * 128 * 2);
    unsigned short* Wt1r  = (unsigned short*)alloc(128 * 128 * 2);
    unsigned short* Wtcat = (unsigned short*)alloc(128 * 128 * 2);

    hipMemsetAsync(gcnt, 0, (size_t)NSB * 4, stream);

    // conversions
    k_cvt_x<<<2048, 256, 0, stream>>>(x, xb, xq, (long)NN * 128 / 8);
    k_cvt_w<<<(128 * 128 + 255) / 256, 256, 0, stream>>>(W1l, Wt1l, 128);
    k_cvt_w<<<(128 * 128 + 255) / 256, 256, 0, stream>>>(W1r, Wt1r, 128);
    k_cvt_wcat<<<(128 * 128 + 255) / 256, 256, 0, stream>>>(W2l, W2r, Wtcat);

    // CSR build: two-level LDS counting sort
    k_binA<<<NBA, 1024, 0, stream>>>(src, dst, gcnt, pairs);
    k_sortB<<<NSB, 1024, 0, stream>>>(gcnt, pairs, offs, deg);

    const int GEMM_GRID = (NN + 127) / 128;   // 782
    // layer 1 (fp8 gather -> bf16 mean -> MFMA dual GEMM)
    k_aggregate_f8<<<(NN + 3) / 4, 256, 0, stream>>>(xq, pairs, offs, deg, meanb);
    k_gemm_mfma<128, true, true><<<GEMM_GRID, 256, 0, stream>>>(meanb, xb, Wt1l, Wt1r, b1, hb);
    // layer 2: g = h@W2l (fp8), z = h@W2r + b2 (bf16), then fused mean+add+log_softmax
    k_gemm_cat<<<GEMM_GRID, 256, 0, stream>>>(hb, Wtcat, b2, gbuf, zbuf);
    k_agg_lsm<<<(NN + 3) / 4, 256, 0, stream>>>(gbuf, zbuf, pairs, offs, deg, out);
}